// Round 5
// baseline (357.573 us; speedup 1.0000x reference)
//
#include <hip/hip_runtime.h>

// ---------------------------------------------------------------------------
// DeepCapsNet forward. conv2 = MFMA (bf16 hh+hl+lh split), fully pipelined:
//   - A (image chunk) register-prefetched into LDS, single-buffered
//   - B (weights) double-buffered in LDS via register relay, XOR-swizzled
// Workspace layout (dwords):
//   h1 : [0,        23658496)  ushort bf16, per (bi,chunk) block of 11552 dw:
//        hiE[4][190][8] | hiO[4][171][8] | loE | loO
//   h2 : [23658496, 34275328)  f32, [b][p=81][co=256]
//   Bt : [34275328, 34570240)  u32, [sidx][cot][hi/lo][n=128][16dw]
//   w3T: [34570240, 34590976)  f32, [p=81][c=256]
// total 138,363,904 bytes
// ---------------------------------------------------------------------------

typedef __attribute__((ext_vector_type(8))) short short8;   // 8 bf16
typedef __attribute__((ext_vector_type(4))) float f32x4;

__device__ __forceinline__ ushort f2bf(float x) {
    uint u = __float_as_uint(x);
    return (ushort)((u + 0x7FFFu + ((u >> 16) & 1u)) >> 16);
}
__device__ __forceinline__ void bfsplit(float x, ushort& h, ushort& l) {
    h = f2bf(x);
    float hf = __uint_as_float(((uint)h) << 16);
    l = f2bf(x - hf);
}

// ---------------- prep: w2 -> Bt pre-tiled bf16 hi/lo fragment images ------
__global__ __launch_bounds__(256) void k_prep_b(
    const float* __restrict__ w2, uint* __restrict__ Bt) {
    __shared__ __align__(16) float wbuf[64 * 288];
    const int sidx = blockIdx.x;          // 0..35
    const int coq  = blockIdx.y;          // 0..3
    const int t = threadIdx.x;
    const int chunk = sidx / 9, tap = sidx - chunk * 9;
    const int co0 = coq * 64;
    for (int idx = t; idx < 4608; idx += 256) {
        const int n = idx / 72, q = idx - n * 72;
        ((float4*)wbuf)[n * 72 + q] =
            *(const float4*)(w2 + (size_t)(co0 + n) * 1152 + chunk * 288 + q * 4);
    }
    __syncthreads();
    const int n = t & 63, dg = (t >> 6) * 4;
    const int cot = coq >> 1, nn = ((coq & 1) * 64) + n;
    uint* dst = Bt + (size_t)(sidx * 2 + cot) * 4096;
#pragma unroll
    for (int dd = 0; dd < 4; ++dd) {
        const int d = dg + dd;
        const float x = wbuf[n * 288 + (2 * d) * 9 + tap];
        const float y = wbuf[n * 288 + (2 * d + 1) * 9 + tap];
        ushort xh, xl, yh, yl;
        bfsplit(x, xh, xl);
        bfsplit(y, yh, yl);
        dst[nn * 16 + d]        = (uint)xh | ((uint)yh << 16);
        dst[2048 + nn * 16 + d] = (uint)xl | ((uint)yl << 16);
    }
}

// ---------------- prep: w3(c,81) -> w3T(p,c) -------------------------------
__global__ __launch_bounds__(256) void k_prep_w3(
    const float* __restrict__ w3, float* __restrict__ w3T) {
    const int p = blockIdx.x, t = threadIdx.x;
    w3T[p * 256 + t] = w3[t * 81 + p];
}

// ---------------- conv1: one block per image, bf16 plane output ------------
__global__ __launch_bounds__(256) void k_conv1(
    const float* __restrict__ x, const float* __restrict__ w,
    const float* __restrict__ bias, const float* __restrict__ g,
    const float* __restrict__ bb, const float* __restrict__ bm,
    const float* __restrict__ bv, ushort* __restrict__ h1) {
    __shared__ __align__(16) float xs[1521];
    __shared__ float wls[1152];
    __shared__ float2 scsh[128];
    const int b = blockIdx.x, t = threadIdx.x;
    const float* xb = x + (size_t)b * 1521;
    for (int i = t; i < 1521; i += 256) xs[i] = xb[i];
    for (int i = t; i < 1152; i += 256) wls[i] = w[i];
    if (t < 128) {
        const float inv = g[t] * rsqrtf(bv[t] + 1e-5f);
        scsh[t] = make_float2(inv, bias[t] * inv + bb[t] - bm[t] * inv);
    }
    __syncthreads();
    ushort* ib = h1 + (size_t)b * 92416;
#pragma unroll
    for (int f = 0; f < 2; ++f) {
        const int p = t + 256 * f;
        if (p >= 361) break;
        const int y = p / 19, xq = p - y * 19;
        const int base = y * 78 + xq * 2;
        const float x0 = xs[base],      x1 = xs[base + 1],  x2 = xs[base + 2];
        const float x3 = xs[base + 39], x4 = xs[base + 40], x5 = xs[base + 41];
        const float x6 = xs[base + 78], x7 = xs[base + 79], x8 = xs[base + 80];
        const int even = ((xq & 1) == 0);
        const int xi = xq >> 1;
        const int posE = y * 10 + xi, posO = y * 9 + xi;
#pragma unroll
        for (int oc = 0; oc < 16; ++oc) {
            short8 hs, ls;
#pragma unroll
            for (int j = 0; j < 8; ++j) {
                const int c = oc * 8 + j;
                const float* wp = wls + c * 9;
                float acc = x0 * wp[0] + x1 * wp[1] + x2 * wp[2] + x3 * wp[3] +
                            x4 * wp[4] + x5 * wp[5] + x6 * wp[6] + x7 * wp[7] + x8 * wp[8];
                const float2 ss = scsh[c];
                const float v = fmaxf(fmaf(acc, ss.x, ss.y), 0.0f);
                ushort hh, lw;
                bfsplit(v, hh, lw);
                hs[j] = (short)hh;
                ls[j] = (short)lw;
            }
            const int chunk = oc >> 2, o = oc & 3;
            ushort* cb = ib + chunk * 23104;
            if (even) {
                *(short8*)(cb + o * 1520 + posE * 8)         = hs;
                *(short8*)(cb + 11552 + o * 1520 + posE * 8) = ls;
            } else {
                *(short8*)(cb + 6080 + o * 1368 + posO * 8)  = hs;
                *(short8*)(cb + 17632 + o * 1368 + posO * 8) = ls;
            }
        }
    }
}

// ---------------- conv2: one block per (image, co-half), pipelined ---------
// M=81 (pad 96), N=128, K = 36 steps (4 chunks x 9 taps) x 32ci.
// 4 waves, wave-tile 48x64. LDS: A image 11552 dw + B dbuf 2x4096 dw = 77.1KB
// -> 2 blocks/CU. One barrier per K-step rotates the B buffer; A chunk c+1 is
// register-prefetched during chunk c's compute; B(s+1) register-relayed.
__global__ __launch_bounds__(256, 2) void k_conv2(
    const uint* __restrict__ h1u, const uint* __restrict__ Bt,
    const float* __restrict__ bias, const float* __restrict__ g,
    const float* __restrict__ bb, const float* __restrict__ bm,
    const float* __restrict__ bv, float* __restrict__ h2) {
    __shared__ __align__(16) uint lds[19744];   // A: [0,11552)  B: [11552,19744)
    const int t = threadIdx.x;
    const int lane = t & 63, wave = t >> 6;
    const int ln15 = lane & 15, lq = lane >> 4;
    const int wm = (wave >> 1) * 48, wn = (wave & 1) * 64;
    const int gg = blockIdx.x;
    const int bi  = ((gg >> 4) << 3) | (gg & 7);   // XCD-pair swizzle
    const int cot = (gg >> 3) & 1;
    const int co0 = cot * 128;

    int PE[3], PO[3];
#pragma unroll
    for (int i = 0; i < 3; ++i) {
        const int m = wm + i * 16 + ln15;
        const int p = m < 81 ? m : 80;
        const int oh = p / 9, ow = p - oh * 9;
        PE[i] = lq * 760 + oh * 80 + ow * 4;
        PO[i] = 3040 + lq * 684 + oh * 72 + ow * 4;
    }
    // B read swizzle offsets per n-tile j: n = wn + j*16 + ln15
    int BRD[4];
#pragma unroll
    for (int j = 0; j < 4; ++j) {
        const int n = wn + j * 16 + ln15;
        BRD[j] = n * 16 + ((lq ^ ((n >> 1) & 3)) << 2);
    }
    // B staging store addresses (thread t owns uint4 idx t + k*256, k=0..3)
    int BST[4];
#pragma unroll
    for (int k = 0; k < 4; ++k) {
        const int idx = t + k * 256;
        const int region = (idx >> 9) & 1;          // 0=hi, 1=lo
        const int n = (idx & 511) >> 2, q = idx & 3;
        BST[k] = region * 2048 + n * 16 + ((q ^ ((n >> 1) & 3)) << 2);
    }

    f32x4 acc[3][4] = {};
    uint4 Aregs[12], Bregs[4];

    // ---- peel: load A(0), B(0)
    {
        const uint4* sa = (const uint4*)(h1u + (size_t)(bi * 4) * 11552);
#pragma unroll
        for (int k = 0; k < 11; ++k) Aregs[k] = sa[t + k * 256];
        if (t < 72) Aregs[11] = sa[t + 11 * 256];
        const uint4* sb = (const uint4*)(Bt + (size_t)cot * 4096);
#pragma unroll
        for (int k = 0; k < 4; ++k) Bregs[k] = sb[t + k * 256];
    }

    for (int c = 0; c < 4; ++c) {
#pragma unroll
        for (int tap = 0; tap < 9; ++tap) {
            const int s = c * 9 + tap;
            const int buf = s & 1;
            uint* ldsB = lds + 11552 + buf * 4096;
            if (tap == 0) {
                __syncthreads();     // prior chunk's A reads done
                uint4* da = (uint4*)lds;
#pragma unroll
                for (int k = 0; k < 11; ++k) da[t + k * 256] = Aregs[k];
                if (t < 72) da[t + 11 * 256] = Aregs[11];
            }
#pragma unroll
            for (int k = 0; k < 4; ++k)
                *(uint4*)(ldsB + BST[k]) = Bregs[k];
            __syncthreads();
            if (tap == 0 && c < 3) {   // prefetch next A chunk into regs
                const uint4* sa = (const uint4*)(h1u + (size_t)(bi * 4 + c + 1) * 11552);
#pragma unroll
                for (int k = 0; k < 11; ++k) Aregs[k] = sa[t + k * 256];
                if (t < 72) Aregs[11] = sa[t + 11 * 256];
            }
            if (s < 35) {              // prefetch next B step into regs
                const uint4* sb = (const uint4*)(Bt + (size_t)((s + 1) * 2 + cot) * 4096);
#pragma unroll
                for (int k = 0; k < 4; ++k) Bregs[k] = sb[t + k * 256];
            }
            // ---- fragments + MFMA
            const int kh = tap / 3, kw = tap - kh * 3;
            const int odd = kw & 1;
            short8 bh[4], bl[4];
#pragma unroll
            for (int j = 0; j < 4; ++j) {
                bh[j] = *reinterpret_cast<const short8*>(ldsB + BRD[j]);
                bl[j] = *reinterpret_cast<const short8*>(ldsB + 2048 + BRD[j]);
            }
            const int sE = kh * 40 + (kw >> 1) * 4;
            const int sO = kh * 36;
#pragma unroll
            for (int i = 0; i < 3; ++i) {
                const int addr = odd ? (PO[i] + sO) : (PE[i] + sE);
                const short8 ah = *reinterpret_cast<const short8*>(lds + addr);
                const short8 al = *reinterpret_cast<const short8*>(lds + addr + 5776);
#pragma unroll
                for (int j = 0; j < 4; ++j) {
                    acc[i][j] = __builtin_amdgcn_mfma_f32_16x16x32_bf16(ah, bh[j], acc[i][j], 0, 0, 0);
                    acc[i][j] = __builtin_amdgcn_mfma_f32_16x16x32_bf16(ah, bl[j], acc[i][j], 0, 0, 0);
                    acc[i][j] = __builtin_amdgcn_mfma_f32_16x16x32_bf16(al, bh[j], acc[i][j], 0, 0, 0);
                }
            }
        }
    }

    // ---- epilogue: bn + relu, h2[bi][p][co]
    float scj[4], shj[4];
#pragma unroll
    for (int j = 0; j < 4; ++j) {
        const int co = co0 + wn + j * 16 + ln15;
        const float inv = g[co] * rsqrtf(bv[co] + 1e-5f);
        scj[j] = inv;
        shj[j] = bias[co] * inv + bb[co] - bm[co] * inv;
    }
#pragma unroll
    for (int i = 0; i < 3; ++i)
#pragma unroll
        for (int r = 0; r < 4; ++r) {
            const int m = wm + i * 16 + lq * 4 + r;
            if (m < 81) {
                float* op = h2 + (size_t)bi * 20736 + m * 256;
#pragma unroll
                for (int j = 0; j < 4; ++j) {
                    const int co = co0 + wn + j * 16 + ln15;
                    op[co] = fmaxf(fmaf(acc[i][j][r], scj[j], shj[j]), 0.0f);
                }
            }
        }
}

// ---------------- fused conv3(depthwise) + squash + 3x fccaps --------------
__device__ __forceinline__ void fccaps_block(
    const int n_l, const int n_h, const int d_h, const float* __restrict__ Wg,
    float* U, float* Uh, float* Sv, float* Av, float* Cv, float* coefs,
    float* outU, const int t) {
    const int nkd = n_h * d_h;
    const int total = n_l * nkd;
    __syncthreads();
    for (int e = t; e < total; e += 256) {
        const int i = e / nkd, rem = e - i * nkd;
        const int k = rem / d_h, l = rem - k * d_h;
        const float* wp = Wg + (size_t)((i * n_h + k) * 8) * d_h + l;
        const float* up = U + i * 8;
        float acc = 0.0f;
#pragma unroll
        for (int j = 0; j < 8; ++j) acc += up[j] * wp[j * d_h];
        Uh[e] = acc;
    }
    __syncthreads();
    for (int e = t; e < nkd; e += 256) {
        float acc = 0.0f;
        for (int i = 0; i < n_l; ++i) acc += Uh[i * nkd + e];
        Sv[e] = acc;
    }
    __syncthreads();
    for (int e = t; e < n_l * n_h; e += 256) {
        const int h = e / n_h, k = e - h * n_h;
        float acc = 0.0f;
        for (int l = 0; l < d_h; ++l)
            acc += Uh[h * nkd + k * d_h + l] * Sv[k * d_h + l];
        Av[e] = acc;
    }
    __syncthreads();
    if (t < n_l) {
        const float invs = 1.0f / 2.8284271247461903f;
        float mx = -1e30f;
        for (int k = 0; k < n_h; ++k) mx = fmaxf(mx, Av[t * n_h + k]);
        float sum = 0.0f;
        for (int k = 0; k < n_h; ++k) {
            const float ev = expf((Av[t * n_h + k] - mx) * invs);
            Cv[t * n_h + k] = ev;
            sum += ev;
        }
        const float r = 1.0f / sum;
        for (int k = 0; k < n_h; ++k) Cv[t * n_h + k] *= r;
    }
    __syncthreads();
    for (int e = t; e < nkd; e += 256) {
        const int k = e / d_h;
        float acc = 0.0f;
        for (int i = 0; i < n_l; ++i) acc += Uh[i * nkd + e] * Cv[i * n_h + k];
        Sv[e] = acc;
    }
    __syncthreads();
    if (t < n_h) {
        float ssq = 0.0f;
        for (int l = 0; l < d_h; ++l) { const float uv = Sv[t * d_h + l]; ssq += uv * uv; }
        const float n = sqrtf(ssq);
        coefs[t] = (1.0f - 1.0f / (expf(n) + 1e-20f)) / (n + 1e-20f);
    }
    __syncthreads();
    for (int e = t; e < nkd; e += 256) outU[e] = Sv[e] * coefs[e / d_h];
}

__global__ __launch_bounds__(256) void k_caps(
    const float* __restrict__ h2, const float* __restrict__ w3T,
    const float* __restrict__ b3, const float* __restrict__ W1,
    const float* __restrict__ W2, const float* __restrict__ W3,
    float* __restrict__ out) {
    __shared__ float U[256];
    __shared__ float Uh[8192];
    __shared__ float Sv[256];
    __shared__ float Av[1024];
    __shared__ float Cv[1024];
    __shared__ float coefs[32];
    const int b = blockIdx.x, t = threadIdx.x;
    {
        const float* hr = h2 + (size_t)b * 20736;
        float acc = 0.0f;
        for (int p = 0; p < 81; ++p) acc += hr[p * 256 + t] * w3T[p * 256 + t];
        U[t] = acc + b3[t];
    }
    __syncthreads();
    if (t < 32) {
        float ssq = 0.0f;
        for (int j = 0; j < 8; ++j) { const float uv = U[t * 8 + j]; ssq += uv * uv; }
        const float n = sqrtf(ssq);
        coefs[t] = (1.0f - 1.0f / (expf(n) + 1e-20f)) / (n + 1e-20f);
    }
    __syncthreads();
    U[t] *= coefs[t >> 3];
    fccaps_block(32, 32,  8, W1, U, Uh, Sv, Av, Cv, coefs, U, t);
    fccaps_block(32, 32,  8, W2, U, Uh, Sv, Av, Cv, coefs, U, t);
    fccaps_block(32, 10, 16, W3, U, Uh, Sv, Av, Cv, coefs, out + (size_t)b * 160, t);
}

// ---------------------------------------------------------------------------
extern "C" void kernel_launch(void* const* d_in, const int* in_sizes, int n_in,
                              void* d_out, int out_size, void* d_ws, size_t ws_size,
                              hipStream_t stream) {
    const float* x    = (const float*)d_in[0];
    const float* c1w  = (const float*)d_in[1];
    const float* c1b  = (const float*)d_in[2];
    const float* bn1g = (const float*)d_in[3];
    const float* bn1b = (const float*)d_in[4];
    const float* bn1m = (const float*)d_in[5];
    const float* bn1v = (const float*)d_in[6];
    const float* c2w  = (const float*)d_in[7];
    const float* c2b  = (const float*)d_in[8];
    const float* bn2g = (const float*)d_in[9];
    const float* bn2b = (const float*)d_in[10];
    const float* bn2m = (const float*)d_in[11];
    const float* bn2v = (const float*)d_in[12];
    const float* c3w  = (const float*)d_in[13];
    const float* c3b  = (const float*)d_in[14];
    const float* W1   = (const float*)d_in[15];
    const float* W2   = (const float*)d_in[16];
    const float* W3   = (const float*)d_in[17];
    float* out = (float*)d_out;
    uint*  wsu = (uint*)d_ws;
    float* wsf = (float*)d_ws;

    ushort* h1  = (ushort*)wsu;          // 23,658,496 dw as bf16 planes
    float*  h2  = wsf + 23658496;        // 10,616,832 dw
    uint*   Bt  = wsu + 34275328;        //    294,912 dw
    float*  w3T = wsf + 34570240;        //     20,736 dw

    k_prep_b<<<dim3(36, 4), 256, 0, stream>>>(c2w, Bt);
    k_prep_w3<<<dim3(81), 256, 0, stream>>>(c3w, w3T);
    k_conv1<<<dim3(512), 256, 0, stream>>>(x, c1w, c1b, bn1g, bn1b, bn1m, bn1v, h1);
    k_conv2<<<dim3(1024), 256, 0, stream>>>((const uint*)h1, Bt, c2b, bn2g, bn2b, bn2m, bn2v, h2);
    k_caps<<<dim3(512), 256, 0, stream>>>(h2, w3T, c3b, W1, W2, W3, out);
}

// Round 6
// 247.288 us; speedup vs baseline: 1.4460x; 1.4460x over previous
//
#include <hip/hip_runtime.h>

// ---------------------------------------------------------------------------
// DeepCapsNet forward. conv2 = MFMA (bf16 hh+hl+lh split), round-4 skeleton +
// B next-tap register prefetch (32 VGPRs, one-tap lifetime) + conv3 fused into
// the conv2 epilogue (h2 never materialized).
// Workspace layout (dwords):
//   h1 : [0,        23658496)  ushort bf16, per (bi,chunk) block of 11552 dw:
//        hiE[4][190][8] | hiO[4][171][8] | loE | loO
//   Uws: [23658496, 23789568)  f32, [b][c=256]  conv3 pre-bias output
//   Bt : [23789568, 24084480)  u32, [sidx][cot][hi/lo][n=128][16dw]
//   w3T: [24084480, 24105216)  f32, [p=81][c=256]
// total 96,420,864 bytes
// ---------------------------------------------------------------------------

typedef __attribute__((ext_vector_type(8))) short short8;   // 8 bf16
typedef __attribute__((ext_vector_type(4))) float f32x4;

__device__ __forceinline__ ushort f2bf(float x) {
    uint u = __float_as_uint(x);
    return (ushort)((u + 0x7FFFu + ((u >> 16) & 1u)) >> 16);
}
__device__ __forceinline__ void bfsplit(float x, ushort& h, ushort& l) {
    h = f2bf(x);
    float hf = __uint_as_float(((uint)h) << 16);
    l = f2bf(x - hf);
}

// ---------------- prep: w2 -> Bt pre-tiled bf16 hi/lo fragment images ------
__global__ __launch_bounds__(256) void k_prep_b(
    const float* __restrict__ w2, uint* __restrict__ Bt) {
    __shared__ __align__(16) float wbuf[64 * 288];
    const int sidx = blockIdx.x;          // 0..35
    const int coq  = blockIdx.y;          // 0..3
    const int t = threadIdx.x;
    const int chunk = sidx / 9, tap = sidx - chunk * 9;
    const int co0 = coq * 64;
    for (int idx = t; idx < 4608; idx += 256) {
        const int n = idx / 72, q = idx - n * 72;
        ((float4*)wbuf)[n * 72 + q] =
            *(const float4*)(w2 + (size_t)(co0 + n) * 1152 + chunk * 288 + q * 4);
    }
    __syncthreads();
    const int n = t & 63, dg = (t >> 6) * 4;
    const int cot = coq >> 1, nn = ((coq & 1) * 64) + n;
    uint* dst = Bt + (size_t)(sidx * 2 + cot) * 4096;
#pragma unroll
    for (int dd = 0; dd < 4; ++dd) {
        const int d = dg + dd;
        const float x = wbuf[n * 288 + (2 * d) * 9 + tap];
        const float y = wbuf[n * 288 + (2 * d + 1) * 9 + tap];
        ushort xh, xl, yh, yl;
        bfsplit(x, xh, xl);
        bfsplit(y, yh, yl);
        dst[nn * 16 + d]        = (uint)xh | ((uint)yh << 16);
        dst[2048 + nn * 16 + d] = (uint)xl | ((uint)yl << 16);
    }
}

// ---------------- prep: w3(c,81) -> w3T(p,c) -------------------------------
__global__ __launch_bounds__(256) void k_prep_w3(
    const float* __restrict__ w3, float* __restrict__ w3T) {
    const int p = blockIdx.x, t = threadIdx.x;
    w3T[p * 256 + t] = w3[t * 81 + p];
}

// ---------------- conv1: one block per image, bf16 plane output ------------
__global__ __launch_bounds__(256) void k_conv1(
    const float* __restrict__ x, const float* __restrict__ w,
    const float* __restrict__ bias, const float* __restrict__ g,
    const float* __restrict__ bb, const float* __restrict__ bm,
    const float* __restrict__ bv, ushort* __restrict__ h1) {
    __shared__ __align__(16) float xs[1521];
    __shared__ float wls[1152];
    __shared__ float2 scsh[128];
    const int b = blockIdx.x, t = threadIdx.x;
    const float* xb = x + (size_t)b * 1521;
    for (int i = t; i < 1521; i += 256) xs[i] = xb[i];
    for (int i = t; i < 1152; i += 256) wls[i] = w[i];
    if (t < 128) {
        const float inv = g[t] * rsqrtf(bv[t] + 1e-5f);
        scsh[t] = make_float2(inv, bias[t] * inv + bb[t] - bm[t] * inv);
    }
    __syncthreads();
    ushort* ib = h1 + (size_t)b * 92416;
#pragma unroll
    for (int f = 0; f < 2; ++f) {
        const int p = t + 256 * f;
        if (p >= 361) break;
        const int y = p / 19, xq = p - y * 19;
        const int base = y * 78 + xq * 2;
        const float x0 = xs[base],      x1 = xs[base + 1],  x2 = xs[base + 2];
        const float x3 = xs[base + 39], x4 = xs[base + 40], x5 = xs[base + 41];
        const float x6 = xs[base + 78], x7 = xs[base + 79], x8 = xs[base + 80];
        const int even = ((xq & 1) == 0);
        const int xi = xq >> 1;
        const int posE = y * 10 + xi, posO = y * 9 + xi;
#pragma unroll
        for (int oc = 0; oc < 16; ++oc) {
            short8 hs, ls;
#pragma unroll
            for (int j = 0; j < 8; ++j) {
                const int c = oc * 8 + j;
                const float* wp = wls + c * 9;
                float acc = x0 * wp[0] + x1 * wp[1] + x2 * wp[2] + x3 * wp[3] +
                            x4 * wp[4] + x5 * wp[5] + x6 * wp[6] + x7 * wp[7] + x8 * wp[8];
                const float2 ss = scsh[c];
                const float v = fmaxf(fmaf(acc, ss.x, ss.y), 0.0f);
                ushort hh, lw;
                bfsplit(v, hh, lw);
                hs[j] = (short)hh;
                ls[j] = (short)lw;
            }
            const int chunk = oc >> 2, o = oc & 3;
            ushort* cb = ib + chunk * 23104;
            if (even) {
                *(short8*)(cb + o * 1520 + posE * 8)         = hs;
                *(short8*)(cb + 11552 + o * 1520 + posE * 8) = ls;
            } else {
                *(short8*)(cb + 6080 + o * 1368 + posO * 8)  = hs;
                *(short8*)(cb + 17632 + o * 1368 + posO * 8) = ls;
            }
        }
    }
}

// ---------------- conv2: one block per (image, co-half) --------------------
// M=81 (pad 96), N=128, K = 4 chunks x 9 taps x 32ci. 4 waves, wave 48x64.
// LDS = one (bi,chunk) h1 block verbatim (46.2 KB) + 512B reduce buffer
// -> 3 blocks/CU. B fragments prefetched one tap ahead in registers (32 VGPR).
// Epilogue fuses conv3: Uws[bi][co] = sum_p relu(bn(conv2)) * w3T[p][co].
__global__ __launch_bounds__(256, 3) void k_conv2(
    const uint* __restrict__ h1u, const uint* __restrict__ Bt,
    const float* __restrict__ g,
    const float* __restrict__ bb, const float* __restrict__ bm,
    const float* __restrict__ bv, const float* __restrict__ bias,
    const float* __restrict__ w3T, float* __restrict__ Uws) {
    __shared__ __align__(16) uint raw[11552];
    __shared__ float ured[128];
    const int t = threadIdx.x;
    const int lane = t & 63, wave = t >> 6;
    const int ln15 = lane & 15, lq = lane >> 4;
    const int wm = (wave >> 1) * 48, wn = (wave & 1) * 64;
    const int gg = blockIdx.x;
    const int bi  = ((gg >> 4) << 3) | (gg & 7);   // XCD-pair swizzle
    const int cot = (gg >> 3) & 1;
    const int co0 = cot * 128;

    int PE[3], PO[3];
#pragma unroll
    for (int i = 0; i < 3; ++i) {
        const int m = wm + i * 16 + ln15;
        const int p = m < 81 ? m : 80;       // pad rows clamp (computed, not stored)
        const int oh = p / 9, ow = p - oh * 9;
        PE[i] = lq * 760 + oh * 80 + ow * 4;
        PO[i] = 3040 + lq * 684 + oh * 72 + ow * 4;
    }
    int BRDg[4];                              // per-lane Bt fragment offsets (dw)
#pragma unroll
    for (int j = 0; j < 4; ++j) {
        const int n = wn + j * 16 + ln15;
        BRDg[j] = n * 16 + lq * 4;
    }

    f32x4 acc[3][4] = {};
    uint4 Bn[8];                              // next-tap B fragments (hi x4, lo x4)
    {   // prologue: prefetch s = 0
        const uint* bp = Bt + (size_t)cot * 4096;
#pragma unroll
        for (int j = 0; j < 4; ++j) {
            Bn[j]     = *(const uint4*)(bp + BRDg[j]);
            Bn[4 + j] = *(const uint4*)(bp + 2048 + BRDg[j]);
        }
    }

#pragma unroll
    for (int c = 0; c < 4; ++c) {
        __syncthreads();
        {   // stage the (bi,chunk) block: clustered loads then stores
            const uint4* src = (const uint4*)(h1u + (size_t)(bi * 4 + c) * 11552);
            uint4* dst = (uint4*)raw;
            uint4 tmp[11];
#pragma unroll
            for (int k = 0; k < 11; ++k) tmp[k] = src[t + k * 256];
            const bool extra = (t < 72);
            uint4 te;
            if (extra) te = src[t + 11 * 256];
#pragma unroll
            for (int k = 0; k < 11; ++k) dst[t + k * 256] = tmp[k];
            if (extra) dst[t + 11 * 256] = te;
        }
        __syncthreads();
#pragma unroll
        for (int tap = 0; tap < 9; ++tap) {
            const int s = c * 9 + tap;
            uint4 Bc[8];
#pragma unroll
            for (int q = 0; q < 8; ++q) Bc[q] = Bn[q];   // renamed by unroll
            if (s < 35) {                                // prefetch next tap
                const uint* bp = Bt + (size_t)((s + 1) * 2 + cot) * 4096;
#pragma unroll
                for (int j = 0; j < 4; ++j) {
                    Bn[j]     = *(const uint4*)(bp + BRDg[j]);
                    Bn[4 + j] = *(const uint4*)(bp + 2048 + BRDg[j]);
                }
            }
            const int kh = tap / 3, kw = tap - kh * 3;
            const int odd = kw & 1;
            const int sE = kh * 40 + (kw >> 1) * 4;
            const int sO = kh * 36;
#pragma unroll
            for (int i = 0; i < 3; ++i) {
                const int addr = odd ? (PO[i] + sO) : (PE[i] + sE);
                const short8 ah = *reinterpret_cast<const short8*>(raw + addr);
                const short8 al = *reinterpret_cast<const short8*>(raw + addr + 5776);
#pragma unroll
                for (int j = 0; j < 4; ++j) {
                    const short8 bh = __builtin_bit_cast(short8, Bc[j]);
                    const short8 bl = __builtin_bit_cast(short8, Bc[4 + j]);
                    acc[i][j] = __builtin_amdgcn_mfma_f32_16x16x32_bf16(ah, bh, acc[i][j], 0, 0, 0);
                    acc[i][j] = __builtin_amdgcn_mfma_f32_16x16x32_bf16(ah, bl, acc[i][j], 0, 0, 0);
                    acc[i][j] = __builtin_amdgcn_mfma_f32_16x16x32_bf16(al, bh, acc[i][j], 0, 0, 0);
                }
            }
        }
    }

    // ---- epilogue: bn + relu + fused depthwise conv3 reduction ------------
    float scj[4], shj[4];
#pragma unroll
    for (int j = 0; j < 4; ++j) {
        const int co = co0 + wn + j * 16 + ln15;
        const float inv = g[co] * rsqrtf(bv[co] + 1e-5f);
        scj[j] = inv;
        shj[j] = bias[co] * inv + bb[co] - bm[co] * inv;
    }
    float usum[4] = {0.f, 0.f, 0.f, 0.f};
#pragma unroll
    for (int i = 0; i < 3; ++i)
#pragma unroll
        for (int r = 0; r < 4; ++r) {
            const int m = wm + i * 16 + lq * 4 + r;
            if (m < 81) {
                const float* wrow = w3T + m * 256 + co0;
#pragma unroll
                for (int j = 0; j < 4; ++j) {
                    const int col = wn + j * 16 + ln15;
                    const float v = fmaxf(fmaf(acc[i][j][r], scj[j], shj[j]), 0.0f);
                    usum[j] = fmaf(v, wrow[col], usum[j]);
                }
            }
        }
#pragma unroll
    for (int j = 0; j < 4; ++j) {             // reduce over lq (p coverage)
        usum[j] += __shfl_xor(usum[j], 16);
        usum[j] += __shfl_xor(usum[j], 32);
    }
    if (lq == 0 && wm == 0) {
#pragma unroll
        for (int j = 0; j < 4; ++j) ured[(wn >> 6) * 64 + j * 16 + ln15] = usum[j];
    }
    __syncthreads();
    if (lq == 0 && wm == 48) {
#pragma unroll
        for (int j = 0; j < 4; ++j) {
            const int col = wn + j * 16 + ln15;
            Uws[(size_t)bi * 256 + co0 + col] =
                usum[j] + ured[(wn >> 6) * 64 + j * 16 + ln15];
        }
    }
}

// ---------------- fused squash + 3x fccaps ---------------------------------
__device__ __forceinline__ void fccaps_block(
    const int n_l, const int n_h, const int d_h, const float* __restrict__ Wg,
    float* U, float* Uh, float* Sv, float* Av, float* Cv, float* coefs,
    float* outU, const int t) {
    const int nkd = n_h * d_h;
    const int total = n_l * nkd;
    __syncthreads();
    for (int e = t; e < total; e += 256) {
        const int i = e / nkd, rem = e - i * nkd;
        const int k = rem / d_h, l = rem - k * d_h;
        const float* wp = Wg + (size_t)((i * n_h + k) * 8) * d_h + l;
        const float* up = U + i * 8;
        float acc = 0.0f;
#pragma unroll
        for (int j = 0; j < 8; ++j) acc += up[j] * wp[j * d_h];
        Uh[e] = acc;
    }
    __syncthreads();
    for (int e = t; e < nkd; e += 256) {
        float acc = 0.0f;
        for (int i = 0; i < n_l; ++i) acc += Uh[i * nkd + e];
        Sv[e] = acc;
    }
    __syncthreads();
    for (int e = t; e < n_l * n_h; e += 256) {
        const int h = e / n_h, k = e - h * n_h;
        float acc = 0.0f;
        for (int l = 0; l < d_h; ++l)
            acc += Uh[h * nkd + k * d_h + l] * Sv[k * d_h + l];
        Av[e] = acc;
    }
    __syncthreads();
    if (t < n_l) {
        const float invs = 1.0f / 2.8284271247461903f;
        float mx = -1e30f;
        for (int k = 0; k < n_h; ++k) mx = fmaxf(mx, Av[t * n_h + k]);
        float sum = 0.0f;
        for (int k = 0; k < n_h; ++k) {
            const float ev = expf((Av[t * n_h + k] - mx) * invs);
            Cv[t * n_h + k] = ev;
            sum += ev;
        }
        const float r = 1.0f / sum;
        for (int k = 0; k < n_h; ++k) Cv[t * n_h + k] *= r;
    }
    __syncthreads();
    for (int e = t; e < nkd; e += 256) {
        const int k = e / d_h;
        float acc = 0.0f;
        for (int i = 0; i < n_l; ++i) acc += Uh[i * nkd + e] * Cv[i * n_h + k];
        Sv[e] = acc;
    }
    __syncthreads();
    if (t < n_h) {
        float ssq = 0.0f;
        for (int l = 0; l < d_h; ++l) { const float uv = Sv[t * d_h + l]; ssq += uv * uv; }
        const float n = sqrtf(ssq);
        coefs[t] = (1.0f - 1.0f / (expf(n) + 1e-20f)) / (n + 1e-20f);
    }
    __syncthreads();
    for (int e = t; e < nkd; e += 256) outU[e] = Sv[e] * coefs[e / d_h];
}

__global__ __launch_bounds__(256) void k_caps(
    const float* __restrict__ Uws, const float* __restrict__ b3,
    const float* __restrict__ W1, const float* __restrict__ W2,
    const float* __restrict__ W3, float* __restrict__ out) {
    __shared__ float U[256];
    __shared__ float Uh[8192];
    __shared__ float Sv[256];
    __shared__ float Av[1024];
    __shared__ float Cv[1024];
    __shared__ float coefs[32];
    const int b = blockIdx.x, t = threadIdx.x;
    U[t] = Uws[(size_t)b * 256 + t] + b3[t];
    __syncthreads();
    if (t < 32) {
        float ssq = 0.0f;
        for (int j = 0; j < 8; ++j) { const float uv = U[t * 8 + j]; ssq += uv * uv; }
        const float n = sqrtf(ssq);
        coefs[t] = (1.0f - 1.0f / (expf(n) + 1e-20f)) / (n + 1e-20f);
    }
    __syncthreads();
    U[t] *= coefs[t >> 3];
    fccaps_block(32, 32,  8, W1, U, Uh, Sv, Av, Cv, coefs, U, t);
    fccaps_block(32, 32,  8, W2, U, Uh, Sv, Av, Cv, coefs, U, t);
    fccaps_block(32, 10, 16, W3, U, Uh, Sv, Av, Cv, coefs, out + (size_t)b * 160, t);
}

// ---------------------------------------------------------------------------
extern "C" void kernel_launch(void* const* d_in, const int* in_sizes, int n_in,
                              void* d_out, int out_size, void* d_ws, size_t ws_size,
                              hipStream_t stream) {
    const float* x    = (const float*)d_in[0];
    const float* c1w  = (const float*)d_in[1];
    const float* c1b  = (const float*)d_in[2];
    const float* bn1g = (const float*)d_in[3];
    const float* bn1b = (const float*)d_in[4];
    const float* bn1m = (const float*)d_in[5];
    const float* bn1v = (const float*)d_in[6];
    const float* c2w  = (const float*)d_in[7];
    const float* c2b  = (const float*)d_in[8];
    const float* bn2g = (const float*)d_in[9];
    const float* bn2b = (const float*)d_in[10];
    const float* bn2m = (const float*)d_in[11];
    const float* bn2v = (const float*)d_in[12];
    const float* c3w  = (const float*)d_in[13];
    const float* c3b  = (const float*)d_in[14];
    const float* W1   = (const float*)d_in[15];
    const float* W2   = (const float*)d_in[16];
    const float* W3   = (const float*)d_in[17];
    float* out = (float*)d_out;
    uint*  wsu = (uint*)d_ws;
    float* wsf = (float*)d_ws;

    ushort* h1  = (ushort*)wsu;          // 23,658,496 dw as bf16 planes
    float*  Uws = wsf + 23658496;        //    131,072 dw
    uint*   Bt  = wsu + 23789568;        //    294,912 dw
    float*  w3T = wsf + 24084480;        //     20,736 dw

    k_prep_b<<<dim3(36, 4), 256, 0, stream>>>(c2w, Bt);
    k_prep_w3<<<dim3(81), 256, 0, stream>>>(c3w, w3T);
    k_conv1<<<dim3(512), 256, 0, stream>>>(x, c1w, c1b, bn1g, bn1b, bn1m, bn1v, h1);
    k_conv2<<<dim3(1024), 256, 0, stream>>>((const uint*)h1, Bt, bn2g, bn2b, bn2m, bn2v,
                                            c2b, w3T, Uws);
    k_caps<<<dim3(512), 256, 0, stream>>>(Uws, c3b, W1, W2, W3, out);
}